// Round 1
// baseline (210.116 us; speedup 1.0000x reference)
//
#include <hip/hip_runtime.h>

// Problem: N_FEAT=12, BATCH=64.
// Key identity: left = min(fl·W, fu·W), right = fu·W where
//   W[m] = sum_{S subset of m, S nonempty} (-1)^{|m\S|} FM[S]
// (Moebius transform of FM over the 12-bit subset lattice). fmat is a
// deterministic 0/1 subset/parity indicator matrix; folded analytically.

#define NB 12
#define NMASK 4096  // 2^12

// ---------------- Kernel 1: build W (single workgroup) ----------------
// Phase A: FM scan as popcount-level DP (deps strictly drop one popcount
//          level, so 12 barrier-separated sweeps reproduce the lax.scan).
// Phase B: clamp to 1.0, set boundary entries.
// Phase C: in-place Moebius transform (12 butterfly passes).
__global__ __launch_bounds__(1024) void k_build_w(
    const float* __restrict__ ie_vars, float* __restrict__ W) {
  __shared__ float g[NMASK];
  const int tid = threadIdx.x;

  // Phase A: masks 1..4094; fm[m] = |v[m-1]| + max_{b in m, m^b >= 1} fm[m^b]
  for (int level = 1; level <= NB; ++level) {
    for (int m = tid; m < NMASK; m += 1024) {
      if (m >= 1 && m <= NMASK - 2 && __popc(m) == level) {
        float best = 0.0f;  // all fm values are >= 0
#pragma unroll
        for (int b = 0; b < NB; ++b) {
          const int p = m - (1 << b);
          if ((m & (1 << b)) && p >= 1) best = fmaxf(best, g[p]);
        }
        g[m] = fabsf(ie_vars[m - 1]) + best;
      }
    }
    __syncthreads();
  }

  // Phase B: FM = min(fm, 1), FM[full]=1, FM[empty]=0 (empty set excluded
  // from fmat's columns; value 0 makes it contribute nothing).
  for (int m = tid; m < NMASK; m += 1024) {
    float val;
    if (m == 0)                val = 0.0f;
    else if (m == NMASK - 1)   val = 1.0f;
    else                       val = fminf(g[m], 1.0f);
    g[m] = val;
  }
  __syncthreads();

  // Phase C: Moebius transform: g[m] -= g[m ^ bit] for m containing bit.
  // No intra-pass hazard: writes touch only masks WITH the bit, reads only
  // masks WITHOUT it.
  for (int b = 0; b < NB; ++b) {
    for (int m = tid; m < NMASK; m += 1024) {
      if (m & (1 << b)) g[m] -= g[m ^ (1 << b)];
    }
    __syncthreads();
  }

  for (int m = tid; m < NMASK; m += 1024) W[m] = g[m];
}

// ---------------- Kernel 2: per-batch dot products ----------------
// Block b handles batch row b. Thread t covers masks [16t, 16t+16):
// product over mask bits = (fixed product of high-8 bits == t) *
// (precomputed 16-entry low-4-bit table). Mask 0 is included harmlessly
// (empty product * W[0] where W[0] == 0).
__global__ __launch_bounds__(256) void k_batch(
    const float* __restrict__ x, const float* __restrict__ W,
    float* __restrict__ out) {
  const int b = blockIdx.x;
  const int tid = threadIdx.x;

  __shared__ float xs[24];  // [0..11]=datal, [12..23]=datau
  if (tid < 24) xs[tid] = x[b * 24 + tid];
  __syncthreads();

  // Low-4-bit product tables (bits 0..3 -> features 0..3).
  float lowl[16], lowu[16];
  lowl[0] = 1.0f;
  lowu[0] = 1.0f;
#pragma unroll
  for (int m = 1; m < 16; ++m) {
    const int lb = __ffs(m) - 1;     // lowest set bit (compile-time here)
    lowl[m] = lowl[m & (m - 1)] * xs[lb];
    lowu[m] = lowu[m & (m - 1)] * xs[12 + lb];
  }

  // High-8-bit fixed product (mask bits 4..11 -> features 4..11).
  const int hm = tid;  // high bits of this thread's mask range
  float hl = 1.0f, hu = 1.0f;
#pragma unroll
  for (int bit = 0; bit < 8; ++bit) {
    if (hm & (1 << bit)) {
      hl *= xs[4 + bit];
      hu *= xs[16 + bit];
    }
  }

  const int base = tid << 4;
  float A = 0.0f, B = 0.0f;  // A = fl.W, B = fu.W (partial)
#pragma unroll
  for (int k = 0; k < 16; ++k) {
    const float w = W[base + k];
    A = fmaf(hl * lowl[k], w, A);
    B = fmaf(hu * lowu[k], w, B);
  }

  // Reduce 256 threads: wave64 shuffle, then 4-wave LDS combine.
#pragma unroll
  for (int off = 32; off > 0; off >>= 1) {
    A += __shfl_down(A, off);
    B += __shfl_down(B, off);
  }
  __shared__ float rA[4], rB[4];
  const int wave = tid >> 6;
  if ((tid & 63) == 0) {
    rA[wave] = A;
    rB[wave] = B;
  }
  __syncthreads();
  if (tid == 0) {
    const float a = rA[0] + rA[1] + rA[2] + rA[3];
    const float bb = rB[0] + rB[1] + rB[2] + rB[3];
    out[b] = fminf(a, bb);   // left
    out[64 + b] = bb;        // right
  }
}

extern "C" void kernel_launch(void* const* d_in, const int* in_sizes, int n_in,
                              void* d_out, int out_size, void* d_ws,
                              size_t ws_size, hipStream_t stream) {
  const float* x  = (const float*)d_in[0];   // (64, 24) fp32
  const float* ie = (const float*)d_in[1];   // (4094, 1) fp32
  // d_in[2] (fmat) is a deterministic 0/1 subset-parity indicator — folded
  // into the Moebius transform analytically; never read.
  float* W   = (float*)d_ws;                 // 4096 floats scratch
  float* out = (float*)d_out;                // 128 floats: left(64), right(64)

  k_build_w<<<1, 1024, 0, stream>>>(ie, W);
  k_batch<<<64, 256, 0, stream>>>(x, W, out);
}